// Round 1
// baseline (451.749 us; speedup 1.0000x reference)
//
#include <hip/hip_runtime.h>

#define BATCH 4
#define N_PER 300
#define IN_DIM 256
#define KEY_DIM 32
#define FH 160
#define FW 160
#define HW (FH * FW)                 // 25600
#define NQ (BATCH * N_PER)           // 1200
#define Q_ELEMS (NQ * KEY_DIM)       // 38400 fp32 in ws: qry_feats [n][c]
#define KWT_ELEMS (IN_DIM * KEY_DIM) // 8192 fp32 in ws: key_w transposed [c][o]

#define QBLOCKS NQ                   // 1200 blocks: one per query row
#define TBLOCKS (KWT_ELEMS / 256)    // 32 transpose blocks
#define NCHUNK (N_PER / 4)           // 75 queries per thread-group in main

// ---------------------------------------------------------------------------
// Prep v2: high-parallelism qry projection + key_w transpose.
// Blocks [0,1200): block n computes qry_feats[n][0..32).
//   thread t: c = t>>3 (output channel), sub = t&7 (k-chunk of 32).
//   Each thread does a float4-vectorized dot-32, then 3x shfl_xor reduces
//   the 8 k-chunks (sub is in the low 3 lane bits -> xor 1/2/4 stays in-group).
// Blocks [1200,1232): transpose key_w[o][c] -> ws kwT[c][o].
// ---------------------------------------------------------------------------
__global__ __launch_bounds__(256) void prep_kernel(
        const float* __restrict__ in_feats,
        const float* __restrict__ qry_w,
        const float* __restrict__ qry_b,
        const float* __restrict__ key_w,
        float* __restrict__ ws) {
    const int bid = blockIdx.x;
    const int t = threadIdx.x;
    if (bid < QBLOCKS) {
        const int n   = bid;
        const int c   = t >> 3;      // 0..31
        const int sub = t & 7;       // 0..7  (k-chunk)
        const float4* __restrict__ f4 =
            (const float4*)(in_feats + n * IN_DIM + sub * 32);
        const float4* __restrict__ w4 =
            (const float4*)(qry_w + c * IN_DIM + sub * 32);
        float a0 = 0.f, a1 = 0.f, a2 = 0.f, a3 = 0.f;
        #pragma unroll
        for (int j = 0; j < 8; ++j) {
            float4 fv = f4[j];
            float4 wv = w4[j];
            a0 += fv.x * wv.x;
            a1 += fv.y * wv.y;
            a2 += fv.z * wv.z;
            a3 += fv.w * wv.w;
        }
        float s = (a0 + a1) + (a2 + a3);
        s += __shfl_xor(s, 1);
        s += __shfl_xor(s, 2);
        s += __shfl_xor(s, 4);
        if (sub == 0) ws[n * KEY_DIM + c] = s + qry_b[c];
    } else {
        const int i = (bid - QBLOCKS) * 256 + t;   // 0..8191
        const int c = i >> 5;                      // 0..255
        const int o = i & 31;                      // 0..31
        ws[Q_ELEMS + i] = key_w[o * IN_DIM + c];   // kwT[c*32 + o]
    }
}

// ---------------------------------------------------------------------------
// Fused main v2: 1024 threads = 256 pixels x 4 groups.
// Phase 1: group g accumulates key[32] over its 64 input channels
//          (feat_map read coalesced, exactly once; kwT rows are wave-uniform
//          scalar loads).
// Reduce:  g0/g1 write the two LDS buffers, g2/g3 add into them, then every
//          thread sums the two ([o][p] layout -> bank-conflict-free).
// Phase 2: group g handles 75 queries for its pixel; key[32] in VGPRs, q rows
//          forced wave-uniform (readfirstlane) -> scalar s_loads; stores
//          coalesced.  key_map never touches HBM; no extra ws needed.
// ---------------------------------------------------------------------------
__global__ __launch_bounds__(1024, 4) void main_kernel(
        const float* __restrict__ feat_map,
        const float* __restrict__ key_b,
        const float* __restrict__ ws,
        float* __restrict__ out) {
    __shared__ float part[2][KEY_DIM][256];        // 64 KB

    const int t   = threadIdx.x;
    const int p   = t & 255;                       // pixel within tile
    const int g   = t >> 8;                        // 0..3
    const int b   = blockIdx.y;
    const int pix = blockIdx.x * 256 + p;

    const float* __restrict__ fb  =
        feat_map + ((size_t)b * IN_DIM + g * 64) * HW + pix;
    const float* __restrict__ kwT = ws + Q_ELEMS + (g * 64) * KEY_DIM;

    float acc[KEY_DIM];
    #pragma unroll
    for (int o = 0; o < KEY_DIM; ++o) acc[o] = 0.f;

    // Phase 1: 64 coalesced feat loads, 64x32 FMA into 32 indep chains.
    #pragma unroll 8
    for (int c = 0; c < 64; ++c) {
        float f = fb[(size_t)c * HW];
        const float* __restrict__ kr = kwT + c * KEY_DIM;
        #pragma unroll
        for (int o = 0; o < KEY_DIM; ++o) acc[o] += kr[o] * f;
    }

    // Cross-group reduction through 2 LDS buffers (fits 64 KB).
    if (g < 2) {
        #pragma unroll
        for (int o = 0; o < KEY_DIM; ++o) part[g][o][p] = acc[o];
    }
    __syncthreads();
    if (g >= 2) {
        #pragma unroll
        for (int o = 0; o < KEY_DIM; ++o) part[g - 2][o][p] += acc[o];
    }
    __syncthreads();

    float key[KEY_DIM];
    #pragma unroll
    for (int o = 0; o < KEY_DIM; ++o)
        key[o] = part[0][o][p] + part[1][o][p] + key_b[o];

    // Phase 2: 75 dot-32s per thread against wave-uniform q rows.
    const int ng = __builtin_amdgcn_readfirstlane(g);
    const float* __restrict__ qb =
        ws + ((size_t)b * N_PER + ng * NCHUNK) * KEY_DIM;
    float* __restrict__ ob =
        out + ((size_t)b * N_PER + (size_t)ng * NCHUNK) * HW + pix;

    for (int n = 0; n < NCHUNK; ++n) {
        const float* __restrict__ qn = qb + n * KEY_DIM;
        float a0 = 0.f, a1 = 0.f, a2 = 0.f, a3 = 0.f;
        #pragma unroll
        for (int c2 = 0; c2 < KEY_DIM; c2 += 4) {
            a0 += qn[c2 + 0] * key[c2 + 0];
            a1 += qn[c2 + 1] * key[c2 + 1];
            a2 += qn[c2 + 2] * key[c2 + 2];
            a3 += qn[c2 + 3] * key[c2 + 3];
        }
        ob[(size_t)n * HW] = (a0 + a1) + (a2 + a3);
    }
}

extern "C" void kernel_launch(void* const* d_in, const int* in_sizes, int n_in,
                              void* d_out, int out_size, void* d_ws, size_t ws_size,
                              hipStream_t stream) {
    const float* in_feats = (const float*)d_in[0];  // [1200, 256]
    const float* feat_map = (const float*)d_in[1];  // [4, 256, 160, 160]
    const float* qry_w    = (const float*)d_in[2];  // [32, 256]
    const float* qry_b    = (const float*)d_in[3];  // [32]
    const float* key_w    = (const float*)d_in[4];  // [32, 256]
    const float* key_b    = (const float*)d_in[5];  // [32]
    float* ws  = (float*)d_ws;                      // needs 46592*4 B
    float* out = (float*)d_out;                     // [1200, 160, 160] fp32

    // Prep: 1200 q-blocks + 32 transpose blocks.
    prep_kernel<<<dim3(QBLOCKS + TBLOCKS), dim3(256), 0, stream>>>(
        in_feats, qry_w, qry_b, key_w, ws);

    // Main: 100 pixel-tiles x 4 batches, 1024 threads each.
    main_kernel<<<dim3(HW / 256, BATCH), dim3(1024), 0, stream>>>(
        feat_map, key_b, ws, out);
}